// Round 1
// baseline (1025.633 us; speedup 1.0000x reference)
//
#include <hip/hip_runtime.h>
#include <hip/hip_bf16.h>

#define NDIM 2048
#define BS   64
#define NITR 25

typedef __bf16 bf16_t;
typedef __bf16 bf16x4 __attribute__((ext_vector_type(4)));
typedef __bf16 bf16x8 __attribute__((ext_vector_type(8)));
typedef float  f32x4  __attribute__((ext_vector_type(4)));

// ---------------------------------------------------------------------------
// Convert H and y to bf16 (no transpose needed: both are used as the
// "row = K-contiguous" operand of NT GEMMs). Also zero traj[0].
// grid: (NDIM*NDIM/4)/256 blocks x 256 threads, one float4 per thread.
// ---------------------------------------------------------------------------
__global__ void convert_kernel(const float* __restrict__ H, const float* __restrict__ y,
                               bf16_t* __restrict__ H16, bf16_t* __restrict__ y16,
                               float* __restrict__ traj0) {
  int idx = blockIdx.x * blockDim.x + threadIdx.x;
  float4 v = ((const float4*)H)[idx];
  bf16x4 o = {(bf16_t)v.x, (bf16_t)v.y, (bf16_t)v.z, (bf16_t)v.w};
  ((bf16x4*)H16)[idx] = o;
  if (idx < BS * NDIM / 4) {
    float4 w = ((const float4*)y)[idx];
    bf16x4 o2 = {(bf16_t)w.x, (bf16_t)w.y, (bf16_t)w.z, (bf16_t)w.w};
    ((bf16x4*)y16)[idx] = o2;
    ((float4*)traj0)[idx] = make_float4(0.f, 0.f, 0.f, 0.f);
  }
}

// ---------------------------------------------------------------------------
// Transpose + convert Dinv, U, invM -> bf16 transposed copies (Dt[n][k] =
// Dinv[k][n], etc.) so the GEMM reads B along K contiguously (NT form).
// 32x32 LDS tile, 33-wide pad (bf16: stride 66B -> 2-way bank alias, free).
// grid: (64,64), block: (32,8).
// ---------------------------------------------------------------------------
__global__ void transpose_kernel(const float* __restrict__ D, const float* __restrict__ U,
                                 const float* __restrict__ M,
                                 bf16_t* __restrict__ Dt, bf16_t* __restrict__ Ut,
                                 bf16_t* __restrict__ Mt) {
  __shared__ bf16_t tile[32][33];
  const float* src[3] = {D, U, M};
  bf16_t* dst[3] = {Dt, Ut, Mt};
  int tx = threadIdx.x, ty = threadIdx.y;
  int bx = blockIdx.x, by = blockIdx.y;
#pragma unroll
  for (int m = 0; m < 3; ++m) {
    __syncthreads();
#pragma unroll
    for (int i = 0; i < 4; ++i) {
      int r = by * 32 + ty + i * 8;
      int c = bx * 32 + tx;
      tile[ty + i * 8][tx] = (bf16_t)src[m][(size_t)r * NDIM + c];
    }
    __syncthreads();
#pragma unroll
    for (int i = 0; i < 4; ++i) {
      int r = bx * 32 + ty + i * 8;  // output row (= source column)
      int c = by * 32 + tx;          // output col (= source row)
      dst[m][(size_t)r * NDIM + c] = tile[tx][ty + i * 8];
    }
  }
}

// ---------------------------------------------------------------------------
// Skinny NT GEMM: C[64, 2048] = add(optional) + sign * (A16 @ Bt16^T)
//   A16 : [64, 2048]  bf16 row-major (K contiguous)
//   Bt16: [2048, 2048] bf16 row-major, Bt16[n][k] = B[k][n]
// 256 threads = 4 waves; wave w computes rows 16w..16w+15; N_tile = 16.
// grid.x = 2048/16 = 128.
// 4 independent accumulators break the serial MFMA chain (1 wave/SIMD here).
// Fragment layouts (m89/m91-verified):
//   A: lane holds A[m = lane&15][k = (lane>>4)*8 + j], j=0..7
//   B: lane holds B[k = (lane>>4)*8 + j][n = lane&15]  == Bt[n][k...]
//   C: lane,reg -> C[row = (lane>>4)*4 + reg][col = lane&15]
// ---------------------------------------------------------------------------
__global__ __launch_bounds__(256) void gemm64_nt(
    const bf16_t* __restrict__ A16, const bf16_t* __restrict__ Bt16,
    const float* __restrict__ add, float sign,
    float* __restrict__ outF32, float* __restrict__ outF32b,
    bf16_t* __restrict__ outB16) {
  int lane  = threadIdx.x & 63;
  int wave  = threadIdx.x >> 6;   // 0..3 -> M stripe
  int mlane = lane & 15;
  int q     = lane >> 4;          // 0..3 -> k-subgroup of 8
  int n0    = blockIdx.x * 16;

  const bf16x8* Arow = (const bf16x8*)(A16 + (size_t)(wave * 16 + mlane) * NDIM) + q;
  const bf16x8* Brow = (const bf16x8*)(Bt16 + (size_t)(n0 + mlane) * NDIM) + q;

  f32x4 acc0 = {0.f, 0.f, 0.f, 0.f};
  f32x4 acc1 = acc0, acc2 = acc0, acc3 = acc0;

#pragma unroll 4
  for (int it = 0; it < 16; ++it) {   // 16 iters x 4 k-chunks of 32 = K 2048
    bf16x8 a0 = Arow[0],  b0 = Brow[0];
    bf16x8 a1 = Arow[4],  b1 = Brow[4];
    bf16x8 a2 = Arow[8],  b2 = Brow[8];
    bf16x8 a3 = Arow[12], b3 = Brow[12];
    acc0 = __builtin_amdgcn_mfma_f32_16x16x32_bf16(a0, b0, acc0, 0, 0, 0);
    acc1 = __builtin_amdgcn_mfma_f32_16x16x32_bf16(a1, b1, acc1, 0, 0, 0);
    acc2 = __builtin_amdgcn_mfma_f32_16x16x32_bf16(a2, b2, acc2, 0, 0, 0);
    acc3 = __builtin_amdgcn_mfma_f32_16x16x32_bf16(a3, b3, acc3, 0, 0, 0);
    Arow += 16;
    Brow += 16;
  }
  f32x4 acc = (acc0 + acc1) + (acc2 + acc3);

  int m = wave * 16 + q * 4;
  int n = n0 + mlane;
#pragma unroll
  for (int r = 0; r < 4; ++r) {
    size_t o = (size_t)(m + r) * NDIM + n;
    float v = sign * acc[r];
    if (add) v += add[o];
    if (outF32)  outF32[o]  = v;
    if (outF32b) outF32b[o] = v;
    if (outB16)  outB16[o]  = (bf16_t)v;
  }
}

// ---------------------------------------------------------------------------
// Host driver: 54 launches, all on `stream`.
// ---------------------------------------------------------------------------
extern "C" void kernel_launch(void* const* d_in, const int* in_sizes, int n_in,
                              void* d_out, int out_size, void* d_ws, size_t ws_size,
                              hipStream_t stream) {
  const float* y    = (const float*)d_in[2];
  const float* H    = (const float*)d_in[3];
  const float* Dinv = (const float*)d_in[4];
  const float* U    = (const float*)d_in[5];
  const float* invM = (const float*)d_in[6];

  float* out     = (float*)d_out;
  float* s_final = out;             // [64,2048]
  float* traj    = out + BS * NDIM; // [26,64,2048]; traj[0] zeroed by convert_kernel

  char* ws = (char*)d_ws;
  size_t off = 0;
  auto alloc = [&](size_t bytes) -> void* {
    void* p = ws + off;
    off += (bytes + 255) & ~(size_t)255;
    return p;
  };
  bf16_t* H16   = (bf16_t*)alloc((size_t)NDIM * NDIM * 2);
  bf16_t* Dt16  = (bf16_t*)alloc((size_t)NDIM * NDIM * 2);
  bf16_t* Ut16  = (bf16_t*)alloc((size_t)NDIM * NDIM * 2);
  bf16_t* iMt16 = (bf16_t*)alloc((size_t)NDIM * NDIM * 2);
  bf16_t* y16   = (bf16_t*)alloc((size_t)BS * NDIM * 2);
  float*  yMF   = (float*)alloc((size_t)BS * NDIM * 4);
  bf16_t* yMF16 = (bf16_t*)alloc((size_t)BS * NDIM * 2);
  bf16_t* s16   = (bf16_t*)alloc((size_t)BS * NDIM * 2);
  bf16_t* t16   = (bf16_t*)alloc((size_t)BS * NDIM * 2);

  // Setup: converts + transposes
  convert_kernel<<<(NDIM * NDIM / 4) / 256, 256, 0, stream>>>(H, y, H16, y16, traj);
  transpose_kernel<<<dim3(NDIM / 32, NDIM / 32), dim3(32, 8), 0, stream>>>(
      Dinv, U, invM, Dt16, Ut16, iMt16);

  dim3 ggrid(NDIM / 16), gblk(256);
  // yMF = y @ H^T  (fp32 copy kept as the per-iteration addend)
  gemm64_nt<<<ggrid, gblk, 0, stream>>>(y16, H16, nullptr, 1.f, yMF, nullptr, yMF16);
  // s_init = yMF @ Dinv
  gemm64_nt<<<ggrid, gblk, 0, stream>>>(yMF16, Dt16, nullptr, 1.f, nullptr, nullptr, s16);

  for (int k = 1; k <= NITR; ++k) {
    // t = yMF - s @ U
    gemm64_nt<<<ggrid, gblk, 0, stream>>>(s16, Ut16, yMF, -1.f, nullptr, nullptr, t16);
    // s = t @ invM   -> traj[k] (and s_final on the last iteration)
    float* f32b = (k == NITR) ? s_final : nullptr;
    gemm64_nt<<<ggrid, gblk, 0, stream>>>(t16, iMt16, nullptr, 1.f,
                                          traj + (size_t)k * BS * NDIM, f32b, s16);
  }
}